// Round 6
// baseline (7599.530 us; speedup 1.0000x reference)
//
#include <hip/hip_runtime.h>
#include <stdint.h>
#include <math.h>

typedef unsigned short ushort_t;
typedef __attribute__((ext_vector_type(8))) short bf16x8;
typedef __attribute__((ext_vector_type(4))) float f32x4;

#define T1_ 32

__device__ __forceinline__ float bf2f(ushort_t u) {
  union { unsigned int i; float f; } v; v.i = ((unsigned int)u) << 16; return v.f;
}
__device__ __forceinline__ ushort_t f2bf(float f) {
  union { float f; unsigned int i; } v; v.f = f;
  unsigned int x = v.i;
  return (ushort_t)((x + 0x7FFFu + ((x >> 16) & 1u)) >> 16); // RNE
}
__device__ __forceinline__ float sigm(float x) { return 1.f / (1.f + expf(-x)); }

__device__ __forceinline__ bf16x8 cvt8(const float* f) {
  const f32x4 lo = *(const f32x4*)f;
  const f32x4 hi = *(const f32x4*)(f + 4);
  bf16x8 r;
  r[0] = (short)f2bf(lo[0]); r[1] = (short)f2bf(lo[1]);
  r[2] = (short)f2bf(lo[2]); r[3] = (short)f2bf(lo[3]);
  r[4] = (short)f2bf(hi[0]); r[5] = (short)f2bf(hi[1]);
  r[6] = (short)f2bf(hi[2]); r[7] = (short)f2bf(hi[3]);
  return r;
}

// ---- f32 -> bf16 strided converter (weights, initial carries) ----
__global__ __launch_bounds__(256) void cvt_k(const float* src, ushort_t* dst,
                                             int rows, int cols, int src_ld, int src_off) {
  const long long idx = (long long)blockIdx.x * 256 + threadIdx.x;
  if (idx >= (long long)rows * cols) return;
  const int row = (int)(idx / cols), col = (int)(idx % cols);
  dst[idx] = f2bf(src[(long long)row * src_ld + src_off + col]);
}

// wpe[n*6+j] = sum_{r<4} W_esp[n][j+6r]   (folds the x4 pose tiling; W_esp f32 (1024x536))
__global__ __launch_bounds__(256) void wpe_k(const float* Wesp, float* wpe) {
  const int i = blockIdx.x * 256 + threadIdx.x;
  if (i >= 1024 * 6) return;
  const int n = i / 6, j = i % 6;
  float s = 0.f;
#pragma unroll
  for (int r = 0; r < 4; ++r) s += Wesp[(long long)n * 536 + j + 6 * r];
  wpe[i] = s;
}

__global__ void marker_k(float* out, float K) {
  if (threadIdx.x == 0 && blockIdx.x == 0) out[0] = K;
}

// ---- GEMM: outb_bf16[1024x1024] = relu(sum_p A_p @ W[:,coff_p:]^T + bias (+pose)) ----
// BM=64, BN=128, BK=32; 256 thr = 4 waves (2x2); wave tile 32x64 (2x4 frags)
struct GemmArgs {
  const void* a0; const void* a1; const void* a2;  // A parts, row-major, kd_p columns
  int kd0, kd1, kd2;
  int coff0, coff1, coff2;
  const ushort_t* W; int ldw;                       // bf16 weights (N x Ktot)
  const float* bias;                                // f32 [1024]
  ushort_t* outb;                                   // bf16 [1024x1024]
  const float* poses; const float* wpe; int t;      // PF only
};
template<int NPARTS, int PF, int A0F32>
__global__ __launch_bounds__(256) void gemm_k(GemmArgs g) {
  __shared__ __align__(16) ushort_t As[2048];
  __shared__ __align__(16) ushort_t Ws[4096];
  const int tid = threadIdx.x;
  const int lane = tid & 63, wave = tid >> 6;
  const int wm = wave >> 1, wn = wave & 1;
  const int bn0 = blockIdx.x * 128, bm0 = blockIdx.y * 64;

  f32x4 acc[2][4];
#pragma unroll
  for (int i = 0; i < 2; ++i)
#pragma unroll
    for (int j = 0; j < 4; ++j) acc[i][j] = (f32x4){0.f, 0.f, 0.f, 0.f};

  const void* ap[3] = { g.a0, g.a1, g.a2 };
  const int kd[3] = { g.kd0, g.kd1, g.kd2 };
  const int cf[3] = { g.coff0, g.coff1, g.coff2 };

  const int rowA = tid >> 2, kcA = (tid & 3) * 8;
  const int rowW2 = rowA + 64;

#pragma unroll 1
  for (int p = 0; p < NPARTS; ++p) {
    const int kdim = kd[p];
    const ushort_t* Wp = g.W + cf[p] + (size_t)bn0 * g.ldw;
    const int nkt = kdim >> 5;
#pragma unroll 1
    for (int kt = 0; kt < nkt; ++kt) {
      const int k0 = kt * 32;
      bf16x8 va;
      const long long aoff = (long long)(bm0 + rowA) * kdim + k0 + kcA;
      if (A0F32 && p == 0) va = cvt8((const float*)ap[p] + aoff);
      else va = *(const bf16x8*)((const ushort_t*)ap[p] + aoff);
      const bf16x8 vw0 = *(const bf16x8*)(Wp + (size_t)rowA * g.ldw + k0 + kcA);
      const bf16x8 vw1 = *(const bf16x8*)(Wp + (size_t)rowW2 * g.ldw + k0 + kcA);
      __syncthreads();
      *(bf16x8*)&As[tid * 8] = va;
      *(bf16x8*)&Ws[tid * 8] = vw0;
      *(bf16x8*)&Ws[(tid + 256) * 8] = vw1;
      __syncthreads();
      const int r15 = lane & 15, kh = (lane >> 4) * 8;
      bf16x8 a[2], b[4];
#pragma unroll
      for (int i = 0; i < 2; ++i)
        a[i] = *(const bf16x8*)&As[(wm * 32 + i * 16 + r15) * 32 + kh];
#pragma unroll
      for (int j = 0; j < 4; ++j)
        b[j] = *(const bf16x8*)&Ws[(wn * 64 + j * 16 + r15) * 32 + kh];
#pragma unroll
      for (int i = 0; i < 2; ++i)
#pragma unroll
        for (int j = 0; j < 4; ++j)
          acc[i][j] = __builtin_amdgcn_mfma_f32_16x16x32_bf16(a[i], b[j], acc[i][j], 0, 0, 0);
    }
  }

  const int r15 = lane & 15, rq = (lane >> 4) * 4;
#pragma unroll
  for (int i = 0; i < 2; ++i) {
#pragma unroll
    for (int j = 0; j < 4; ++j) {
      const int col = bn0 + wn * 64 + j * 16 + r15;
      const float bs = g.bias[col];
#pragma unroll
      for (int q = 0; q < 4; ++q) {
        const int row = bm0 + wm * 32 + i * 16 + rq + q;
        float v = acc[i][j][q] + bs;
        if (PF) {
          const long long pb = ((long long)g.t * 1024 + row) * 6;
          float s = 0.f;
#pragma unroll
          for (int jj = 0; jj < 6; ++jj) s += g.poses[pb + jj] * g.wpe[col * 6 + jj];
          v += s;
        }
        v = fmaxf(v, 0.f);
        g.outb[(size_t)row * 1024 + col] = f2bf(v);
      }
    }
  }
}

// ---- fused GRU: dst_f32 / dstb_bf16 = GRUCell(x, h) ----
// BM=64, BN=64 (of D=1024), 6 gate accumulators, K=1024
struct GruArgs {
  const ushort_t* x;     // bf16 [1024x1024]
  const ushort_t* hb;    // bf16 shadow of carry [1024x1024]
  const float* hf;       // f32 carry [1024x1024]
  const ushort_t* wih; const ushort_t* whh;  // bf16 [3072x1024]
  const float* bih; const float* bhh;        // f32 [3072]
  float* dst; ushort_t* dstb;
};
__global__ __launch_bounds__(256) void grufuse_k(GruArgs g) {
  __shared__ __align__(16) ushort_t Xs[2048];
  __shared__ __align__(16) ushort_t Hs[2048];
  __shared__ __align__(16) ushort_t Wt[6][2048];
  const int tid = threadIdx.x;
  const int lane = tid & 63, wave = tid >> 6;
  const int wm = wave >> 1, wn = wave & 1;
  const int bn0 = blockIdx.x * 64, bm0 = blockIdx.y * 64;

  f32x4 acc[6][2][2];
#pragma unroll
  for (int gg = 0; gg < 6; ++gg)
#pragma unroll
    for (int i = 0; i < 2; ++i)
#pragma unroll
      for (int j = 0; j < 2; ++j) acc[gg][i][j] = (f32x4){0.f, 0.f, 0.f, 0.f};

  const int rowA = tid >> 2, kc = (tid & 3) * 8;

#pragma unroll 1
  for (int kt = 0; kt < 32; ++kt) {
    const int k0 = kt * 32;
    const bf16x8 vx = *(const bf16x8*)(g.x + (size_t)(bm0 + rowA) * 1024 + k0 + kc);
    const bf16x8 vh = *(const bf16x8*)(g.hb + (size_t)(bm0 + rowA) * 1024 + k0 + kc);
    bf16x8 vw[6];
#pragma unroll
    for (int gg = 0; gg < 6; ++gg) {
      const ushort_t* base = (gg < 3) ? g.wih : g.whh;
      const int grow = (gg % 3) * 1024 + bn0 + rowA;
      vw[gg] = *(const bf16x8*)(base + (size_t)grow * 1024 + k0 + kc);
    }
    __syncthreads();
    *(bf16x8*)&Xs[tid * 8] = vx;
    *(bf16x8*)&Hs[tid * 8] = vh;
#pragma unroll
    for (int gg = 0; gg < 6; ++gg) *(bf16x8*)&Wt[gg][tid * 8] = vw[gg];
    __syncthreads();
    const int r15 = lane & 15, kh = (lane >> 4) * 8;
    bf16x8 ax[2], ah[2];
#pragma unroll
    for (int i = 0; i < 2; ++i) {
      ax[i] = *(const bf16x8*)&Xs[(wm * 32 + i * 16 + r15) * 32 + kh];
      ah[i] = *(const bf16x8*)&Hs[(wm * 32 + i * 16 + r15) * 32 + kh];
    }
#pragma unroll
    for (int gg = 0; gg < 6; ++gg) {
      bf16x8 bw[2];
#pragma unroll
      for (int j = 0; j < 2; ++j)
        bw[j] = *(const bf16x8*)&Wt[gg][(wn * 32 + j * 16 + r15) * 32 + kh];
#pragma unroll
      for (int i = 0; i < 2; ++i)
#pragma unroll
        for (int j = 0; j < 2; ++j)
          acc[gg][i][j] = __builtin_amdgcn_mfma_f32_16x16x32_bf16(
              (gg < 3) ? ax[i] : ah[i], bw[j], acc[gg][i][j], 0, 0, 0);
    }
  }

  const int r15 = lane & 15, rq = (lane >> 4) * 4;
#pragma unroll
  for (int j = 0; j < 2; ++j) {
    const int col = bn0 + wn * 32 + j * 16 + r15;
    const float br = g.bih[col],        bhr = g.bhh[col];
    const float bz = g.bih[col + 1024], bhz = g.bhh[col + 1024];
    const float bn_ = g.bih[col + 2048], bhn = g.bhh[col + 2048];
#pragma unroll
    for (int i = 0; i < 2; ++i) {
#pragma unroll
      for (int q = 0; q < 4; ++q) {
        const int row = bm0 + wm * 32 + i * 16 + rq + q;
        const float ir = acc[0][i][j][q] + br,   hr = acc[3][i][j][q] + bhr;
        const float iz = acc[1][i][j][q] + bz,   hz = acc[4][i][j][q] + bhz;
        const float in_ = acc[2][i][j][q] + bn_, hn = acc[5][i][j][q] + bhn;
        const float r = sigm(ir + hr);
        const float z = sigm(iz + hz);
        const float ng = tanhf(in_ + r * hn);
        const long long o = (long long)row * 1024 + col;
        const float bnew = (1.f - z) * ng + z * g.hf[o];
        g.dst[o] = bnew;
        g.dstb[o] = f2bf(bnew);
      }
    }
  }
}

// ---- fused head: raw = hh @ Ws^T (+b); mean/std/state written f32, state shadow bf16 ----
// Ws is (512x1024): rows [0,256) mean, [256,512) raw. BM=64, BN=64 (of 256 cols), grid (4,16)
struct HeadArgs {
  const ushort_t* hh;    // bf16 [1024x1024]
  const ushort_t* Ws;    // bf16 [512x1024]
  const float* bs;       // f32 [512]
  const float* noise;    // f32 slice [1024x256]
  float* omean; float* ostd; float* ostate;  // f32 [1024x256]
  ushort_t* stateb;      // bf16 shadow [1024x256]
};
__global__ __launch_bounds__(256) void headfuse_k(HeadArgs g) {
  __shared__ __align__(16) ushort_t As[2048];
  __shared__ __align__(16) ushort_t Wt[2][2048];
  const int tid = threadIdx.x;
  const int lane = tid & 63, wave = tid >> 6;
  const int wm = wave >> 1, wn = wave & 1;
  const int bn0 = blockIdx.x * 64, bm0 = blockIdx.y * 64;

  f32x4 acc[2][2][2];
#pragma unroll
  for (int gg = 0; gg < 2; ++gg)
#pragma unroll
    for (int i = 0; i < 2; ++i)
#pragma unroll
      for (int j = 0; j < 2; ++j) acc[gg][i][j] = (f32x4){0.f, 0.f, 0.f, 0.f};

  const int rowA = tid >> 2, kc = (tid & 3) * 8;

#pragma unroll 1
  for (int kt = 0; kt < 32; ++kt) {
    const int k0 = kt * 32;
    const bf16x8 va = *(const bf16x8*)(g.hh + (size_t)(bm0 + rowA) * 1024 + k0 + kc);
    bf16x8 vw[2];
#pragma unroll
    for (int gg = 0; gg < 2; ++gg)
      vw[gg] = *(const bf16x8*)(g.Ws + (size_t)(gg * 256 + bn0 + rowA) * 1024 + k0 + kc);
    __syncthreads();
    *(bf16x8*)&As[tid * 8] = va;
#pragma unroll
    for (int gg = 0; gg < 2; ++gg) *(bf16x8*)&Wt[gg][tid * 8] = vw[gg];
    __syncthreads();
    const int r15 = lane & 15, kh = (lane >> 4) * 8;
    bf16x8 a[2];
#pragma unroll
    for (int i = 0; i < 2; ++i)
      a[i] = *(const bf16x8*)&As[(wm * 32 + i * 16 + r15) * 32 + kh];
#pragma unroll
    for (int gg = 0; gg < 2; ++gg) {
      bf16x8 bw[2];
#pragma unroll
      for (int j = 0; j < 2; ++j)
        bw[j] = *(const bf16x8*)&Wt[gg][(wn * 32 + j * 16 + r15) * 32 + kh];
#pragma unroll
      for (int i = 0; i < 2; ++i)
#pragma unroll
        for (int j = 0; j < 2; ++j)
          acc[gg][i][j] = __builtin_amdgcn_mfma_f32_16x16x32_bf16(a[i], bw[j], acc[gg][i][j], 0, 0, 0);
    }
  }

  const int r15 = lane & 15, rq = (lane >> 4) * 4;
#pragma unroll
  for (int j = 0; j < 2; ++j) {
    const int col = bn0 + wn * 32 + j * 16 + r15;   // 0..255
    const float bm = g.bs[col];
    const float bsd = g.bs[col + 256];
#pragma unroll
    for (int i = 0; i < 2; ++i) {
#pragma unroll
      for (int q = 0; q < 4; ++q) {
        const int row = bm0 + wm * 32 + i * 16 + rq + q;
        const float mean = acc[0][i][j][q] + bm;
        const float rs = acc[1][i][j][q] + bsd;
        const float sp = fmaxf(rs, 0.f) + log1pf(expf(-fabsf(rs)));
        const float sd = sp + 0.1f;
        const long long o = (long long)row * 256 + col;
        const float st = mean + sd * g.noise[o];
        g.omean[o] = mean; g.ostd[o] = sd; g.ostate[o] = st;
        g.stateb[o] = f2bf(st);
      }
    }
  }
}

extern "C" void kernel_launch(void* const* d_in, const int* in_sizes, int n_in,
                              void* d_out, int out_size, void* d_ws, size_t ws_size,
                              hipStream_t stream) {
  float* out = (float*)d_out;

  // Guards -> marker K = gid*2^24 + wsMB (decodable from absmax)
  int gid = 0;
  if (n_in != 26) gid = 1;
  else if (out_size != 83886080) gid = 2;
  else if (in_sizes[0] != 262144 || in_sizes[1] != 1048576 || in_sizes[2] != 33554432 ||
           in_sizes[3] != 196608 || in_sizes[4] != 8388608 || in_sizes[5] != 8388608) gid = 3;
  else if (in_sizes[6] != 1572864 || in_sizes[8] != 548864) gid = 4;
  else if (in_sizes[10] != 3145728 || in_sizes[11] != 3145728 ||
           in_sizes[14] != 3145728 || in_sizes[15] != 3145728) gid = 5;
  else if (in_sizes[18] != 1048576 || in_sizes[20] != 524288 ||
           in_sizes[22] != 1048576 || in_sizes[24] != 524288) gid = 6;
  else if (ws_size < (56ull << 20)) gid = 7;
  if (gid != 0) {
    unsigned wsMB = (unsigned)(ws_size >> 20); if (wsMB > 4095u) wsMB = 4095u;
    const float K = (float)gid * 16777216.0f + (float)wsMB;
    hipLaunchKernelGGL(marker_k, dim3(1), dim3(64), 0, stream, out, K);
    return;
  }

  const float* prev_state  = (const float*)d_in[0];   // (1024,256)
  const float* prev_belief = (const float*)d_in[1];   // (1024,1024)
  const float* observations= (const float*)d_in[2];   // (32,1024,1024)
  const float* poses       = (const float*)d_in[3];   // (32,1024,6)
  const float* noise_post  = (const float*)d_in[4];   // (32,1024,256)
  const float* noise_prior = (const float*)d_in[5];
  const float* W_esq = (const float*)d_in[6];  const float* b_esq = (const float*)d_in[7];
  const float* W_esp = (const float*)d_in[8];  const float* b_esp = (const float*)d_in[9];
  const float* gq_wih = (const float*)d_in[10]; const float* gq_whh = (const float*)d_in[11];
  const float* gq_bih = (const float*)d_in[12]; const float* gq_bhh = (const float*)d_in[13];
  const float* gp_wih = (const float*)d_in[14]; const float* gp_whh = (const float*)d_in[15];
  const float* gp_bih = (const float*)d_in[16]; const float* gp_bhh = (const float*)d_in[17];
  const float* W_ebq = (const float*)d_in[18]; const float* b_ebq = (const float*)d_in[19];
  const float* W_sq  = (const float*)d_in[20]; const float* b_sq  = (const float*)d_in[21];
  const float* W_ebp = (const float*)d_in[22]; const float* b_ebp = (const float*)d_in[23];
  const float* W_sp  = (const float*)d_in[24]; const float* b_sp  = (const float*)d_in[25];

  // Output channel bases (f32 elements)
  float* out_belief = out;                    // (32,1024,1024)
  float* out_pstate = out + 33554432LL;       // (32,1024,256) each below
  float* out_pmean  = out + 41943040LL;
  float* out_pstd   = out + 50331648LL;
  float* out_qstate = out + 58720256LL;
  float* out_qmean  = out + 67108864LL;
  float* out_qstd   = out + 75497472LL;

  // Workspace layout (bytes)
  char* w = (char*)d_ws;
  ushort_t* wWesq = (ushort_t*)(w);                  // 1024x1536
  ushort_t* wWesp = (ushort_t*)(w + 3145728);        // 1024x512 (cols 24..535)
  ushort_t* wGqih = (ushort_t*)(w + 4194304);        // 3072x1024
  ushort_t* wGqhh = (ushort_t*)(w + 10485760);
  ushort_t* wGpih = (ushort_t*)(w + 16777216);
  ushort_t* wGphh = (ushort_t*)(w + 23068672);
  ushort_t* wEbq  = (ushort_t*)(w + 29360128);       // 1024x1024
  ushort_t* wEbp  = (ushort_t*)(w + 31457280);
  ushort_t* wSq   = (ushort_t*)(w + 33554432);       // 512x1024
  ushort_t* wSp   = (ushort_t*)(w + 34603008);
  float*    wpe   = (float*)(w + 35651584);          // 1024x6 f32
  ushort_t* h_q   = (ushort_t*)(w + 37748736);       // 1024x1024 bf16
  ushort_t* h_p   = (ushort_t*)(w + 39845888);
  ushort_t* bqb   = (ushort_t*)(w + 41943040);       // 1024x1024 bf16 shadow
  ushort_t* bpb   = (ushort_t*)(w + 44040192);
  ushort_t* sqb   = (ushort_t*)(w + 46137344);       // 1024x256 bf16 shadow
  ushort_t* spb   = (ushort_t*)(w + 46661632);
  float*    bpf0  = (float*)(w + 47185920);          // 1024x1024 f32
  float*    bpf1  = (float*)(w + 51380224);

  const dim3 blk(256);
  auto cvt = [&](const float* s, ushort_t* d, int r, int c, int ld, int off) {
    const long long n = (long long)r * c;
    hipLaunchKernelGGL(cvt_k, dim3((unsigned)((n + 255) / 256)), blk, 0, stream, s, d, r, c, ld, off);
  };
  cvt(W_esq, wWesq, 1024, 1536, 1536, 0);
  cvt(W_esp, wWesp, 1024, 512, 536, 24);
  cvt(gq_wih, wGqih, 3072, 1024, 1024, 0);
  cvt(gq_whh, wGqhh, 3072, 1024, 1024, 0);
  cvt(gp_wih, wGpih, 3072, 1024, 1024, 0);
  cvt(gp_whh, wGphh, 3072, 1024, 1024, 0);
  cvt(W_ebq, wEbq, 1024, 1024, 1024, 0);
  cvt(W_ebp, wEbp, 1024, 1024, 1024, 0);
  cvt(W_sq, wSq, 512, 1024, 1024, 0);
  cvt(W_sp, wSp, 512, 1024, 1024, 0);
  cvt(prev_state, sqb, 1024, 256, 256, 0);
  cvt(prev_state, spb, 1024, 256, 256, 0);
  cvt(prev_belief, bqb, 1024, 1024, 1024, 0);
  cvt(prev_belief, bpb, 1024, 1024, 1024, 0);
  hipLaunchKernelGGL(wpe_k, dim3(24), blk, 0, stream, W_esp, wpe);

  for (int t = 0; t < T1_; ++t) {
    const float* obs_t = observations + (long long)t * 1048576;
    const float* bq_prev_f = (t == 0) ? prev_belief : out_belief + (long long)(t - 1) * 1048576;
    const float* bp_prev_f = (t == 0) ? prev_belief : ((t & 1) ? bpf0 : bpf1);
    float* bp_cur = (t & 1) ? bpf1 : bpf0;

    // 1) h_q = relu([obs | s_q | s_p] @ W_esq^T + b)
    GemmArgs a{};
    a.a0 = obs_t; a.a1 = sqb; a.a2 = spb;
    a.kd0 = 1024; a.kd1 = 256; a.kd2 = 256;
    a.coff0 = 0; a.coff1 = 1024; a.coff2 = 1280;
    a.W = wWesq; a.ldw = 1536; a.bias = b_esq; a.outb = h_q;
    hipLaunchKernelGGL((gemm_k<3,0,1>), dim3(8,16), blk, 0, stream, a);

    // 2) h_p = relu([pose(folded) | s_q | s_p] @ W_esp^T + b)
    a = GemmArgs{};
    a.a0 = sqb; a.a1 = spb;
    a.kd0 = 256; a.kd1 = 256;
    a.coff0 = 0; a.coff1 = 256;
    a.W = wWesp; a.ldw = 512; a.bias = b_esp; a.outb = h_p;
    a.poses = poses; a.wpe = wpe; a.t = t;
    hipLaunchKernelGGL((gemm_k<2,1,0>), dim3(8,16), blk, 0, stream, a);

    // 3) posterior GRU -> out ch0[t] f32 + bqb shadow
    GruArgs gr{};
    gr.x = h_q; gr.hb = bqb; gr.hf = bq_prev_f;
    gr.wih = wGqih; gr.whh = wGqhh; gr.bih = gq_bih; gr.bhh = gq_bhh;
    gr.dst = out_belief + (long long)t * 1048576; gr.dstb = bqb;
    hipLaunchKernelGGL(grufuse_k, dim3(16,16), blk, 0, stream, gr);

    // 4) hh_q = relu(b_q @ W_ebq^T + b) -> h_q (reuse)
    a = GemmArgs{};
    a.a0 = bqb; a.kd0 = 1024; a.coff0 = 0;
    a.W = wEbq; a.ldw = 1024; a.bias = b_ebq; a.outb = h_q;
    hipLaunchKernelGGL((gemm_k<1,0,0>), dim3(8,16), blk, 0, stream, a);

    // 5) posterior head -> qmean/qstd/qstate + sqb shadow
    HeadArgs hd{};
    hd.hh = h_q; hd.Ws = wSq; hd.bs = b_sq;
    hd.noise = noise_post + (long long)t * 262144;
    hd.omean  = out_qmean  + (long long)t * 262144;
    hd.ostd   = out_qstd   + (long long)t * 262144;
    hd.ostate = out_qstate + (long long)t * 262144;
    hd.stateb = sqb;
    hipLaunchKernelGGL(headfuse_k, dim3(4,16), blk, 0, stream, hd);

    // 6) prior GRU -> bp ping/pong + bpb shadow
    gr = GruArgs{};
    gr.x = h_p; gr.hb = bpb; gr.hf = bp_prev_f;
    gr.wih = wGpih; gr.whh = wGphh; gr.bih = gp_bih; gr.bhh = gp_bhh;
    gr.dst = bp_cur; gr.dstb = bpb;
    hipLaunchKernelGGL(grufuse_k, dim3(16,16), blk, 0, stream, gr);

    // 7) hh_p = relu(b_p @ W_ebp^T + b) -> h_p (reuse)
    a = GemmArgs{};
    a.a0 = bpb; a.kd0 = 1024; a.coff0 = 0;
    a.W = wEbp; a.ldw = 1024; a.bias = b_ebp; a.outb = h_p;
    hipLaunchKernelGGL((gemm_k<1,0,0>), dim3(8,16), blk, 0, stream, a);

    // 8) prior head -> pmean/pstd/pstate + spb shadow
    hd = HeadArgs{};
    hd.hh = h_p; hd.Ws = wSp; hd.bs = b_sp;
    hd.noise = noise_prior + (long long)t * 262144;
    hd.omean  = out_pmean  + (long long)t * 262144;
    hd.ostd   = out_pstd   + (long long)t * 262144;
    hd.ostate = out_pstate + (long long)t * 262144;
    hd.stateb = spb;
    hipLaunchKernelGGL(headfuse_k, dim3(4,16), blk, 0, stream, hd);
  }
}

// Round 7
// 4067.091 us; speedup vs baseline: 1.8685x; 1.8685x over previous
//
#include <hip/hip_runtime.h>
#include <stdint.h>
#include <math.h>

typedef unsigned short ushort_t;
typedef __attribute__((ext_vector_type(8))) short bf16x8;
typedef __attribute__((ext_vector_type(4))) float f32x4;

#define T1_ 32

__device__ __forceinline__ float bf2f(ushort_t u) {
  union { unsigned int i; float f; } v; v.i = ((unsigned int)u) << 16; return v.f;
}
__device__ __forceinline__ ushort_t f2bf(float f) {
  union { float f; unsigned int i; } v; v.f = f;
  unsigned int x = v.i;
  return (ushort_t)((x + 0x7FFFu + ((x >> 16) & 1u)) >> 16); // RNE
}
__device__ __forceinline__ float sigm(float x) { return 1.f / (1.f + expf(-x)); }

// async global->LDS, 16B per lane. LDS dest must be wave-uniform base (+lane*16 by HW).
__device__ __forceinline__ void gld16(const ushort_t* g, ushort_t* l) {
  __builtin_amdgcn_global_load_lds(
      (const __attribute__((address_space(1))) unsigned int*)g,
      (__attribute__((address_space(3))) unsigned int*)l, 16, 0, 0);
}

// ---- f32 -> bf16 strided converter ----
__global__ __launch_bounds__(256) void cvt_k(const float* src, ushort_t* dst,
                                             long long n, int cols, int src_ld, int src_off) {
  const long long idx = (long long)blockIdx.x * 256 + threadIdx.x;
  if (idx >= n) return;
  const long long row = idx / cols;
  const int col = (int)(idx - row * cols);
  dst[idx] = f2bf(src[row * src_ld + src_off + col]);
}

// wpe[n*6+j] = sum_{r<4} W_esp[n][j+6r]  (W_esp f32 (1024x536))
__global__ __launch_bounds__(256) void wpe_k(const float* Wesp, float* wpe) {
  const int i = blockIdx.x * 256 + threadIdx.x;
  if (i >= 1024 * 6) return;
  const int n = i / 6, j = i % 6;
  float s = 0.f;
#pragma unroll
  for (int r = 0; r < 4; ++r) s += Wesp[(long long)n * 536 + j + 6 * r];
  wpe[i] = s;
}

__global__ void marker_k(float* out, float K) {
  if (threadIdx.x == 0 && blockIdx.x == 0) out[0] = K;
}

// ---- fused 2-sided GEMM (z selects side): out_bf16[1024x1024] = relu(sum_p A_p@W^T + b (+pose)) ----
// BM=64, BN=128, BK=32; 256 thr = 4 waves (2x2); wave tile 32x64 (2x4 frags)
struct MMSide {
  const ushort_t* a0; const ushort_t* a1; const ushort_t* a2;
  int kd0, kd1, kd2;
  int coff0, coff1, coff2;
  int nparts;
  const ushort_t* W; int ldw;
  const float* bias;
  ushort_t* outb;
  int dopose;
};
struct MM2Args { MMSide s[2]; const float* poses_t; const float* wpe; };

__global__ __launch_bounds__(256) void mm2_k(MM2Args g) {
  const MMSide S = g.s[blockIdx.z];
  __shared__ __align__(16) ushort_t As[2048];
  __shared__ __align__(16) ushort_t Ws[4096];
  const int tid = threadIdx.x;
  const int lane = tid & 63, wave = tid >> 6;
  const int wm = wave >> 1, wn = wave & 1;
  const int bn0 = blockIdx.x * 128, bm0 = blockIdx.y * 64;

  f32x4 acc[2][4];
#pragma unroll
  for (int i = 0; i < 2; ++i)
#pragma unroll
    for (int j = 0; j < 4; ++j) acc[i][j] = (f32x4){0.f, 0.f, 0.f, 0.f};

  const ushort_t* ap[3] = { S.a0, S.a1, S.a2 };
  const int kd[3] = { S.kd0, S.kd1, S.kd2 };
  const int cf[3] = { S.coff0, S.coff1, S.coff2 };

  const int rowA = tid >> 2, kcA = (tid & 3) * 8;
  ushort_t* ldsA  = &As[wave * 512];
  ushort_t* ldsW0 = &Ws[wave * 512];
  ushort_t* ldsW1 = &Ws[2048 + wave * 512];

#pragma unroll 1
  for (int p = 0; p < S.nparts; ++p) {
    const int kdim = kd[p];
    const ushort_t* Ap = ap[p] + (long long)bm0 * kdim + (long long)rowA * kdim + kcA;
    const ushort_t* Wp0 = S.W + cf[p] + (long long)(bn0 + rowA) * S.ldw + kcA;
    const ushort_t* Wp1 = Wp0 + (long long)64 * S.ldw;
    const int nkt = kdim >> 5;
#pragma unroll 1
    for (int kt = 0; kt < nkt; ++kt) {
      const int k0 = kt * 32;
      __syncthreads();  // previous iteration's ds_reads complete before DMA overwrite
      gld16(Ap + k0, ldsA);
      gld16(Wp0 + k0, ldsW0);
      gld16(Wp1 + k0, ldsW1);
      __syncthreads();  // drains vmcnt (compiler emits waitcnt before barrier)
      const int r15 = lane & 15, kh = (lane >> 4) * 8;
      bf16x8 a[2], b[4];
#pragma unroll
      for (int i = 0; i < 2; ++i)
        a[i] = *(const bf16x8*)&As[(wm * 32 + i * 16 + r15) * 32 + kh];
#pragma unroll
      for (int j = 0; j < 4; ++j)
        b[j] = *(const bf16x8*)&Ws[(wn * 64 + j * 16 + r15) * 32 + kh];
#pragma unroll
      for (int i = 0; i < 2; ++i)
#pragma unroll
        for (int j = 0; j < 4; ++j)
          acc[i][j] = __builtin_amdgcn_mfma_f32_16x16x32_bf16(a[i], b[j], acc[i][j], 0, 0, 0);
    }
  }

  const int r15 = lane & 15, rq = (lane >> 4) * 4;
#pragma unroll
  for (int i = 0; i < 2; ++i) {
#pragma unroll
    for (int j = 0; j < 4; ++j) {
      const int col = bn0 + wn * 64 + j * 16 + r15;
      const float bs = S.bias[col];
#pragma unroll
      for (int q = 0; q < 4; ++q) {
        const int row = bm0 + wm * 32 + i * 16 + rq + q;
        float v = acc[i][j][q] + bs;
        if (S.dopose) {
          float s = 0.f;
#pragma unroll
          for (int jj = 0; jj < 6; ++jj)
            s += g.poses_t[(long long)row * 6 + jj] * g.wpe[col * 6 + jj];
          v += s;
        }
        v = fmaxf(v, 0.f);
        S.outb[(size_t)row * 1024 + col] = f2bf(v);
      }
    }
  }
}

// ---- fused 2-sided GRU (z selects q/p): dst_f32 / dstb_bf16 = GRUCell(x, h) ----
struct GruSide {
  const ushort_t* x;     // bf16 [1024x1024]
  const ushort_t* hb;    // bf16 carry shadow (read)
  const float* hf;       // f32 carry (read)
  const ushort_t* wih; const ushort_t* whh;  // bf16 [3072x1024]
  const float* bih; const float* bhh;        // f32 [3072]
  float* dst; ushort_t* dstb;                // write (dstb != hb: ping-pong)
};
struct Gru2Args { GruSide s[2]; };

__global__ __launch_bounds__(256) void gru2_k(Gru2Args g) {
  const GruSide S = g.s[blockIdx.z];
  __shared__ __align__(16) ushort_t Xs[2048];
  __shared__ __align__(16) ushort_t Hs[2048];
  __shared__ __align__(16) ushort_t Wt[6][2048];
  const int tid = threadIdx.x;
  const int lane = tid & 63, wave = tid >> 6;
  const int wm = wave >> 1, wn = wave & 1;
  const int bn0 = blockIdx.x * 64, bm0 = blockIdx.y * 64;

  f32x4 acc[6][2][2];
#pragma unroll
  for (int gg = 0; gg < 6; ++gg)
#pragma unroll
    for (int i = 0; i < 2; ++i)
#pragma unroll
      for (int j = 0; j < 2; ++j) acc[gg][i][j] = (f32x4){0.f, 0.f, 0.f, 0.f};

  const int rowA = tid >> 2, kc = (tid & 3) * 8;
  const long long xoff = (long long)(bm0 + rowA) * 1024 + kc;

#pragma unroll 1
  for (int kt = 0; kt < 32; ++kt) {
    const int k0 = kt * 32;
    __syncthreads();
    gld16(S.x + xoff + k0, &Xs[wave * 512]);
    gld16(S.hb + xoff + k0, &Hs[wave * 512]);
#pragma unroll
    for (int gg = 0; gg < 6; ++gg) {
      const ushort_t* base = (gg < 3) ? S.wih : S.whh;
      const int grow = (gg % 3) * 1024 + bn0 + rowA;
      gld16(base + (long long)grow * 1024 + k0 + kc, &Wt[gg][wave * 512]);
    }
    __syncthreads();
    const int r15 = lane & 15, kh = (lane >> 4) * 8;
    bf16x8 ax[2], ah[2];
#pragma unroll
    for (int i = 0; i < 2; ++i) {
      ax[i] = *(const bf16x8*)&Xs[(wm * 32 + i * 16 + r15) * 32 + kh];
      ah[i] = *(const bf16x8*)&Hs[(wm * 32 + i * 16 + r15) * 32 + kh];
    }
#pragma unroll
    for (int gg = 0; gg < 6; ++gg) {
      bf16x8 bw[2];
#pragma unroll
      for (int j = 0; j < 2; ++j)
        bw[j] = *(const bf16x8*)&Wt[gg][(wn * 32 + j * 16 + r15) * 32 + kh];
#pragma unroll
      for (int i = 0; i < 2; ++i)
#pragma unroll
        for (int j = 0; j < 2; ++j)
          acc[gg][i][j] = __builtin_amdgcn_mfma_f32_16x16x32_bf16(
              (gg < 3) ? ax[i] : ah[i], bw[j], acc[gg][i][j], 0, 0, 0);
    }
  }

  const int r15 = lane & 15, rq = (lane >> 4) * 4;
#pragma unroll
  for (int j = 0; j < 2; ++j) {
    const int col = bn0 + wn * 32 + j * 16 + r15;
    const float br  = S.bih[col],        bhr = S.bhh[col];
    const float bz  = S.bih[col + 1024], bhz = S.bhh[col + 1024];
    const float bn_ = S.bih[col + 2048], bhn = S.bhh[col + 2048];
#pragma unroll
    for (int i = 0; i < 2; ++i) {
#pragma unroll
      for (int q = 0; q < 4; ++q) {
        const int row = bm0 + wm * 32 + i * 16 + rq + q;
        const float ir = acc[0][i][j][q] + br,   hr = acc[3][i][j][q] + bhr;
        const float iz = acc[1][i][j][q] + bz,   hz = acc[4][i][j][q] + bhz;
        const float in_ = acc[2][i][j][q] + bn_, hn = acc[5][i][j][q] + bhn;
        const float r = sigm(ir + hr);
        const float z = sigm(iz + hz);
        const float ng = tanhf(in_ + r * hn);
        const long long o = (long long)row * 1024 + col;
        const float bnew = (1.f - z) * ng + z * S.hf[o];
        S.dst[o] = bnew;
        S.dstb[o] = f2bf(bnew);
      }
    }
  }
}

// ---- fused 2-sided head (z selects q/p) ----
struct HeadSide {
  const ushort_t* hh;    // bf16 [1024x1024]
  const ushort_t* Ws;    // bf16 [512x1024]: rows [0,256)=mean, [256,512)=raw
  const float* bs;       // f32 [512]
  const float* noise;    // f32 [1024x256]
  float* omean; float* ostd; float* ostate;
  ushort_t* stateb;      // bf16 shadow [1024x256]
};
struct Head2Args { HeadSide s[2]; };

__global__ __launch_bounds__(256) void head2_k(Head2Args g) {
  const HeadSide S = g.s[blockIdx.z];
  __shared__ __align__(16) ushort_t As[2048];
  __shared__ __align__(16) ushort_t Wt[2][2048];
  const int tid = threadIdx.x;
  const int lane = tid & 63, wave = tid >> 6;
  const int wm = wave >> 1, wn = wave & 1;
  const int bn0 = blockIdx.x * 64, bm0 = blockIdx.y * 64;

  f32x4 acc[2][2][2];
#pragma unroll
  for (int gg = 0; gg < 2; ++gg)
#pragma unroll
    for (int i = 0; i < 2; ++i)
#pragma unroll
      for (int j = 0; j < 2; ++j) acc[gg][i][j] = (f32x4){0.f, 0.f, 0.f, 0.f};

  const int rowA = tid >> 2, kc = (tid & 3) * 8;
  const long long aoff = (long long)(bm0 + rowA) * 1024 + kc;

#pragma unroll 1
  for (int kt = 0; kt < 32; ++kt) {
    const int k0 = kt * 32;
    __syncthreads();
    gld16(S.hh + aoff + k0, &As[wave * 512]);
#pragma unroll
    for (int gg = 0; gg < 2; ++gg)
      gld16(S.Ws + (long long)(gg * 256 + bn0 + rowA) * 1024 + k0 + kc, &Wt[gg][wave * 512]);
    __syncthreads();
    const int r15 = lane & 15, kh = (lane >> 4) * 8;
    bf16x8 a[2];
#pragma unroll
    for (int i = 0; i < 2; ++i)
      a[i] = *(const bf16x8*)&As[(wm * 32 + i * 16 + r15) * 32 + kh];
#pragma unroll
    for (int gg = 0; gg < 2; ++gg) {
      bf16x8 bw[2];
#pragma unroll
      for (int j = 0; j < 2; ++j)
        bw[j] = *(const bf16x8*)&Wt[gg][(wn * 32 + j * 16 + r15) * 32 + kh];
#pragma unroll
      for (int i = 0; i < 2; ++i)
#pragma unroll
        for (int j = 0; j < 2; ++j)
          acc[gg][i][j] = __builtin_amdgcn_mfma_f32_16x16x32_bf16(a[i], bw[j], acc[gg][i][j], 0, 0, 0);
    }
  }

  const int r15 = lane & 15, rq = (lane >> 4) * 4;
#pragma unroll
  for (int j = 0; j < 2; ++j) {
    const int col = bn0 + wn * 32 + j * 16 + r15;   // 0..255
    const float bm = S.bs[col];
    const float bsd = S.bs[col + 256];
#pragma unroll
    for (int i = 0; i < 2; ++i) {
#pragma unroll
      for (int q = 0; q < 4; ++q) {
        const int row = bm0 + wm * 32 + i * 16 + rq + q;
        const float mean = acc[0][i][j][q] + bm;
        const float rs = acc[1][i][j][q] + bsd;
        const float sp = fmaxf(rs, 0.f) + log1pf(expf(-fabsf(rs)));
        const float sd = sp + 0.1f;
        const long long o = (long long)row * 256 + col;
        const float st = mean + sd * S.noise[o];
        S.omean[o] = mean; S.ostd[o] = sd; S.ostate[o] = st;
        S.stateb[o] = f2bf(st);
      }
    }
  }
}

extern "C" void kernel_launch(void* const* d_in, const int* in_sizes, int n_in,
                              void* d_out, int out_size, void* d_ws, size_t ws_size,
                              hipStream_t stream) {
  float* out = (float*)d_out;

  int gid = 0;
  if (n_in != 26) gid = 1;
  else if (out_size != 83886080) gid = 2;
  else if (in_sizes[0] != 262144 || in_sizes[1] != 1048576 || in_sizes[2] != 33554432 ||
           in_sizes[3] != 196608 || in_sizes[4] != 8388608 || in_sizes[5] != 8388608) gid = 3;
  else if (in_sizes[6] != 1572864 || in_sizes[8] != 548864) gid = 4;
  else if (in_sizes[10] != 3145728 || in_sizes[11] != 3145728 ||
           in_sizes[14] != 3145728 || in_sizes[15] != 3145728) gid = 5;
  else if (in_sizes[18] != 1048576 || in_sizes[20] != 524288 ||
           in_sizes[22] != 1048576 || in_sizes[24] != 524288) gid = 6;
  else if (ws_size < (128ull << 20)) gid = 7;
  if (gid != 0) {
    unsigned wsMB = (unsigned)(ws_size >> 20); if (wsMB > 4095u) wsMB = 4095u;
    const float K = (float)gid * 16777216.0f + (float)wsMB;
    hipLaunchKernelGGL(marker_k, dim3(1), dim3(64), 0, stream, out, K);
    return;
  }

  const float* prev_state  = (const float*)d_in[0];
  const float* prev_belief = (const float*)d_in[1];
  const float* observations= (const float*)d_in[2];
  const float* poses       = (const float*)d_in[3];
  const float* noise_post  = (const float*)d_in[4];
  const float* noise_prior = (const float*)d_in[5];
  const float* W_esq = (const float*)d_in[6];  const float* b_esq = (const float*)d_in[7];
  const float* W_esp = (const float*)d_in[8];  const float* b_esp = (const float*)d_in[9];
  const float* gq_wih = (const float*)d_in[10]; const float* gq_whh = (const float*)d_in[11];
  const float* gq_bih = (const float*)d_in[12]; const float* gq_bhh = (const float*)d_in[13];
  const float* gp_wih = (const float*)d_in[14]; const float* gp_whh = (const float*)d_in[15];
  const float* gp_bih = (const float*)d_in[16]; const float* gp_bhh = (const float*)d_in[17];
  const float* W_ebq = (const float*)d_in[18]; const float* b_ebq = (const float*)d_in[19];
  const float* W_sq  = (const float*)d_in[20]; const float* b_sq  = (const float*)d_in[21];
  const float* W_ebp = (const float*)d_in[22]; const float* b_ebp = (const float*)d_in[23];
  const float* W_sp  = (const float*)d_in[24]; const float* b_sp  = (const float*)d_in[25];

  float* out_belief = out;
  float* out_pstate = out + 33554432LL;
  float* out_pmean  = out + 41943040LL;
  float* out_pstd   = out + 50331648LL;
  float* out_qstate = out + 58720256LL;
  float* out_qmean  = out + 67108864LL;
  float* out_qstd   = out + 75497472LL;

  char* w = (char*)d_ws;
  ushort_t* obsb  = (ushort_t*)(w);                     // [0,64)MB
  ushort_t* wWesq = (ushort_t*)(w + (64ull << 20));     // 1024x1536
  ushort_t* wWesp = (ushort_t*)(w + (67ull << 20));     // 1024x512
  ushort_t* wGqih = (ushort_t*)(w + (68ull << 20));     // 3072x1024
  ushort_t* wGqhh = (ushort_t*)(w + (74ull << 20));
  ushort_t* wGpih = (ushort_t*)(w + (80ull << 20));
  ushort_t* wGphh = (ushort_t*)(w + (86ull << 20));
  ushort_t* wEbq  = (ushort_t*)(w + (92ull << 20));     // 1024x1024
  ushort_t* wEbp  = (ushort_t*)(w + (94ull << 20));
  ushort_t* wSq   = (ushort_t*)(w + (96ull << 20));     // 512x1024
  ushort_t* wSp   = (ushort_t*)(w + (97ull << 20));
  float*    wpe   = (float*)(w + (98ull << 20));        // 1024x6
  ushort_t* h_q   = (ushort_t*)(w + (99ull << 20));     // 1024x1024
  ushort_t* h_p   = (ushort_t*)(w + (101ull << 20));
  ushort_t* bqb[2] = { (ushort_t*)(w + (103ull << 20)), (ushort_t*)(w + (105ull << 20)) };
  ushort_t* bpb[2] = { (ushort_t*)(w + (107ull << 20)), (ushort_t*)(w + (109ull << 20)) };
  ushort_t* sqb   = (ushort_t*)(w + (111ull << 20));    // 1024x256
  ushort_t* spb   = (ushort_t*)(w + (111ull << 20) + 524288);
  float*    bpf[2] = { (float*)(w + (112ull << 20)), (float*)(w + (116ull << 20)) };

  const dim3 blk(256);
  auto cvt = [&](const float* s, ushort_t* d, long long n, int c, int ld, int off) {
    hipLaunchKernelGGL(cvt_k, dim3((unsigned)((n + 255) / 256)), blk, 0, stream, s, d, n, c, ld, off);
  };
  cvt(observations, obsb, 33554432LL, 1024, 1024, 0);
  cvt(W_esq, wWesq, 1572864LL, 1536, 1536, 0);
  cvt(W_esp, wWesp, 524288LL, 512, 536, 24);
  cvt(gq_wih, wGqih, 3145728LL, 1024, 1024, 0);
  cvt(gq_whh, wGqhh, 3145728LL, 1024, 1024, 0);
  cvt(gp_wih, wGpih, 3145728LL, 1024, 1024, 0);
  cvt(gp_whh, wGphh, 3145728LL, 1024, 1024, 0);
  cvt(W_ebq, wEbq, 1048576LL, 1024, 1024, 0);
  cvt(W_ebp, wEbp, 1048576LL, 1024, 1024, 0);
  cvt(W_sq, wSq, 524288LL, 1024, 1024, 0);
  cvt(W_sp, wSp, 524288LL, 1024, 1024, 0);
  cvt(prev_state, sqb, 262144LL, 256, 256, 0);
  cvt(prev_state, spb, 262144LL, 256, 256, 0);
  cvt(prev_belief, bqb[1], 1048576LL, 1024, 1024, 0);
  cvt(prev_belief, bpb[1], 1048576LL, 1024, 1024, 0);
  hipLaunchKernelGGL(wpe_k, dim3(24), blk, 0, stream, W_esp, wpe);

  for (int t = 0; t < T1_; ++t) {
    const int cur = t & 1, prv = cur ^ 1;
    const ushort_t* obs_t = obsb + (long long)t * 1048576;
    const float* bq_prev_f = (t == 0) ? prev_belief : out_belief + (long long)(t - 1) * 1048576;
    const float* bp_prev_f = (t == 0) ? prev_belief : bpf[prv];

    // 1) embed: z=0 h_q, z=1 h_p (+pose)
    MM2Args a{};
    a.s[0] = MMSide{ obs_t, sqb, spb, 1024, 256, 256, 0, 1024, 1280, 3,
                     wWesq, 1536, b_esq, h_q, 0 };
    a.s[1] = MMSide{ sqb, spb, nullptr, 256, 256, 0, 0, 256, 0, 2,
                     wWesp, 512, b_esp, h_p, 1 };
    a.poses_t = poses + (long long)t * 6144; a.wpe = wpe;
    hipLaunchKernelGGL(mm2_k, dim3(8, 16, 2), blk, 0, stream, a);

    // 2) GRU: z=0 posterior (-> out ch0[t], bqb[cur]); z=1 prior (-> bpf[cur], bpb[cur])
    Gru2Args gr{};
    gr.s[0] = GruSide{ h_q, bqb[prv], bq_prev_f, wGqih, wGqhh, gq_bih, gq_bhh,
                       out_belief + (long long)t * 1048576, bqb[cur] };
    gr.s[1] = GruSide{ h_p, bpb[prv], bp_prev_f, wGpih, wGphh, gp_bih, gp_bhh,
                       bpf[cur], bpb[cur] };
    hipLaunchKernelGGL(gru2_k, dim3(16, 16, 2), blk, 0, stream, gr);

    // 3) belief->hidden: z=0 hh_q -> h_q, z=1 hh_p -> h_p
    a = MM2Args{};
    a.s[0] = MMSide{ bqb[cur], nullptr, nullptr, 1024, 0, 0, 0, 0, 0, 1,
                     wEbq, 1024, b_ebq, h_q, 0 };
    a.s[1] = MMSide{ bpb[cur], nullptr, nullptr, 1024, 0, 0, 0, 0, 0, 1,
                     wEbp, 1024, b_ebp, h_p, 0 };
    hipLaunchKernelGGL(mm2_k, dim3(8, 16, 2), blk, 0, stream, a);

    // 4) heads: z=0 posterior (qmean/qstd/qstate + sqb), z=1 prior
    Head2Args hd{};
    hd.s[0] = HeadSide{ h_q, wSq, b_sq, noise_post + (long long)t * 262144,
                        out_qmean + (long long)t * 262144,
                        out_qstd + (long long)t * 262144,
                        out_qstate + (long long)t * 262144, sqb };
    hd.s[1] = HeadSide{ h_p, wSp, b_sp, noise_prior + (long long)t * 262144,
                        out_pmean + (long long)t * 262144,
                        out_pstd + (long long)t * 262144,
                        out_pstate + (long long)t * 262144, spb };
    hipLaunchKernelGGL(head2_k, dim3(4, 16, 2), blk, 0, stream, hd);
  }
}

// Round 8
// 4034.787 us; speedup vs baseline: 1.8835x; 1.0080x over previous
//
#include <hip/hip_runtime.h>
#include <stdint.h>
#include <math.h>

typedef unsigned short ushort_t;
typedef __attribute__((ext_vector_type(8))) short bf16x8;
typedef __attribute__((ext_vector_type(4))) float f32x4;

#define T1_ 32

__device__ __forceinline__ float bf2f(ushort_t u) {
  union { unsigned int i; float f; } v; v.i = ((unsigned int)u) << 16; return v.f;
}
__device__ __forceinline__ ushort_t f2bf(float f) {
  union { float f; unsigned int i; } v; v.f = f;
  unsigned int x = v.i;
  return (ushort_t)((x + 0x7FFFu + ((x >> 16) & 1u)) >> 16); // RNE
}
__device__ __forceinline__ float sigm(float x) { return 1.f / (1.f + expf(-x)); }

// async global->LDS, 16B per lane (dest = wave-uniform base + lane*16).
__device__ __forceinline__ void gld16(const ushort_t* g, ushort_t* l) {
  __builtin_amdgcn_global_load_lds(
      (const __attribute__((address_space(1))) unsigned int*)g,
      (__attribute__((address_space(3))) unsigned int*)l, 16, 0, 0);
}

__global__ __launch_bounds__(256) void cvt_k(const float* src, ushort_t* dst,
                                             long long n, int cols, int src_ld, int src_off) {
  const long long idx = (long long)blockIdx.x * 256 + threadIdx.x;
  if (idx >= n) return;
  const long long row = idx / cols;
  const int col = (int)(idx - row * cols);
  dst[idx] = f2bf(src[row * src_ld + src_off + col]);
}

__global__ __launch_bounds__(256) void wpe_k(const float* Wesp, float* wpe) {
  const int i = blockIdx.x * 256 + threadIdx.x;
  if (i >= 1024 * 6) return;
  const int n = i / 6, j = i % 6;
  float s = 0.f;
#pragma unroll
  for (int r = 0; r < 4; ++r) s += Wesp[(long long)n * 536 + j + 6 * r];
  wpe[i] = s;
}

__global__ void marker_k(float* out, float K) {
  if (threadIdx.x == 0 && blockIdx.x == 0) out[0] = K;
}

// ---- fused 2-sided GEMM: out_bf16[1024x1024] = relu(sum_p A_p@W^T + b (+pose)) ----
// BM=64, BN=128, BK=32; 256 thr; double-buffered (stage t+1 || compute t, 1 barrier/tile)
struct MMSide {
  const ushort_t* a0; const ushort_t* a1; const ushort_t* a2;
  int kd0, kd1, kd2;
  int coff0, coff1, coff2;
  const ushort_t* W; int ldw;
  const float* bias;
  ushort_t* outb;
  int dopose;
};
struct MM2Args { MMSide s[2]; const float* poses_t; const float* wpe; };

__global__ __launch_bounds__(256) void mm2_k(MM2Args g) {
  const MMSide S = g.s[blockIdx.z];
  __shared__ __align__(16) ushort_t As[2][2048];
  __shared__ __align__(16) ushort_t Ws[2][4096];
  const int tid = threadIdx.x;
  const int lane = tid & 63, wave = tid >> 6;
  const int wm = wave >> 1, wn = wave & 1;
  const int bn0 = blockIdx.x * 128, bm0 = blockIdx.y * 64;

  f32x4 acc[2][4];
#pragma unroll
  for (int i = 0; i < 2; ++i)
#pragma unroll
    for (int j = 0; j < 4; ++j) acc[i][j] = (f32x4){0.f, 0.f, 0.f, 0.f};

  const int rowA = tid >> 2, kcA = (tid & 3) * 8;
  const int nk0 = S.kd0 >> 5, nk1 = S.kd1 >> 5, nk2 = S.kd2 >> 5;
  const int c1 = nk0, c2 = nk0 + nk1, nkt = c2 + nk2;

  auto stage = [&](int buf, int ktg) {
    const ushort_t* ab; int ktl, kdim, cf;
    if (ktg < c1)      { ab = S.a0; ktl = ktg;      kdim = S.kd0; cf = S.coff0; }
    else if (ktg < c2) { ab = S.a1; ktl = ktg - c1; kdim = S.kd1; cf = S.coff1; }
    else               { ab = S.a2; ktl = ktg - c2; kdim = S.kd2; cf = S.coff2; }
    const int k0 = ktl * 32;
    gld16(ab + (long long)(bm0 + rowA) * kdim + k0 + kcA, &As[buf][wave * 512]);
    gld16(S.W + cf + (long long)(bn0 + rowA) * S.ldw + k0 + kcA, &Ws[buf][wave * 512]);
    gld16(S.W + cf + (long long)(bn0 + 64 + rowA) * S.ldw + k0 + kcA, &Ws[buf][2048 + wave * 512]);
  };

  stage(0, 0);
  __syncthreads();
  int cur = 0;
#pragma unroll 1
  for (int ktg = 0; ktg < nkt; ++ktg) {
    if (ktg + 1 < nkt) stage(cur ^ 1, ktg + 1);
    const int r15 = lane & 15, kh = (lane >> 4) * 8;
    bf16x8 a[2], b[4];
#pragma unroll
    for (int i = 0; i < 2; ++i)
      a[i] = *(const bf16x8*)&As[cur][(wm * 32 + i * 16 + r15) * 32 + kh];
#pragma unroll
    for (int j = 0; j < 4; ++j)
      b[j] = *(const bf16x8*)&Ws[cur][(wn * 64 + j * 16 + r15) * 32 + kh];
#pragma unroll
    for (int i = 0; i < 2; ++i)
#pragma unroll
      for (int j = 0; j < 4; ++j)
        acc[i][j] = __builtin_amdgcn_mfma_f32_16x16x32_bf16(a[i], b[j], acc[i][j], 0, 0, 0);
    __syncthreads();
    cur ^= 1;
  }

  const int r15 = lane & 15, rq = (lane >> 4) * 4;
#pragma unroll
  for (int i = 0; i < 2; ++i) {
#pragma unroll
    for (int j = 0; j < 4; ++j) {
      const int col = bn0 + wn * 64 + j * 16 + r15;
      const float bs = S.bias[col];
#pragma unroll
      for (int q = 0; q < 4; ++q) {
        const int row = bm0 + wm * 32 + i * 16 + rq + q;
        float v = acc[i][j][q] + bs;
        if (S.dopose) {
          float s = 0.f;
#pragma unroll
          for (int jj = 0; jj < 6; ++jj)
            s += g.poses_t[(long long)row * 6 + jj] * g.wpe[col * 6 + jj];
          v += s;
        }
        v = fmaxf(v, 0.f);
        S.outb[(size_t)row * 1024 + col] = f2bf(v);
      }
    }
  }
}

// ---- fused 2-sided GRU: BM=128, BN=64, 512 thr (8 waves 4x2), double-buffered ----
struct GruSide {
  const ushort_t* x;     // bf16 [1024x1024]
  const ushort_t* hb;    // bf16 carry shadow (read)
  const float* hf;       // f32 carry (read)
  const ushort_t* wih; const ushort_t* whh;  // bf16 [3072x1024]
  const float* bih; const float* bhh;        // f32 [3072]
  float* dst; ushort_t* dstb;                // ping-pong: dstb != hb
};
struct Gru2Args { GruSide s[2]; };

__global__ __launch_bounds__(512) void gru2_k(Gru2Args g) {
  const GruSide S = g.s[blockIdx.z];
  __shared__ __align__(16) ushort_t Xs[2][4096];       // 128x32
  __shared__ __align__(16) ushort_t Hs[2][4096];       // 128x32
  __shared__ __align__(16) ushort_t Wt[2][6][2048];    // 6 gates x 64x32
  const int tid = threadIdx.x;           // 0..511
  const int lane = tid & 63, wave = tid >> 6;          // 8 waves
  const int wm = wave >> 1, wn = wave & 1;             // 4 x 2
  const int bn0 = blockIdx.x * 64, bm0 = blockIdx.y * 128;

  f32x4 acc[6][2][2];
#pragma unroll
  for (int gg = 0; gg < 6; ++gg)
#pragma unroll
    for (int i = 0; i < 2; ++i)
#pragma unroll
      for (int j = 0; j < 2; ++j) acc[gg][i][j] = (f32x4){0.f, 0.f, 0.f, 0.f};

  const int rowA = tid >> 2, kc = (tid & 3) * 8;       // rows 0..127
  const long long xoff = (long long)(bm0 + rowA) * 1024 + kc;

  auto stage = [&](int buf, int kt) {
    const int k0 = kt * 32;
    gld16(S.x + xoff + k0, &Xs[buf][wave * 512]);
    gld16(S.hb + xoff + k0, &Hs[buf][wave * 512]);
#pragma unroll
    for (int r = 0; r < 3; ++r) {
      const int q = tid + 512 * r;                      // 0..1535 chunks
      const int gg = q >> 8;                            // gate 0..5 (wave-uniform)
      const int qq = q & 255;
      const int wrow = qq >> 2, wkc = (qq & 3) * 8;
      const ushort_t* base = (gg < 3) ? S.wih : S.whh;
      const int grow = (gg % 3) * 1024 + bn0 + wrow;
      gld16(base + (long long)grow * 1024 + k0 + wkc,
            &Wt[buf][0][0] + wave * 512 + r * 4096);
    }
  };

  stage(0, 0);
  __syncthreads();
  int cur = 0;
#pragma unroll 1
  for (int kt = 0; kt < 32; ++kt) {
    if (kt + 1 < 32) stage(cur ^ 1, kt + 1);
    const int r15 = lane & 15, kh = (lane >> 4) * 8;
    bf16x8 ax[2], ah[2];
#pragma unroll
    for (int i = 0; i < 2; ++i) {
      ax[i] = *(const bf16x8*)&Xs[cur][(wm * 32 + i * 16 + r15) * 32 + kh];
      ah[i] = *(const bf16x8*)&Hs[cur][(wm * 32 + i * 16 + r15) * 32 + kh];
    }
#pragma unroll
    for (int gg = 0; gg < 6; ++gg) {
      bf16x8 bw[2];
#pragma unroll
      for (int j = 0; j < 2; ++j)
        bw[j] = *(const bf16x8*)&Wt[cur][gg][(wn * 32 + j * 16 + r15) * 32 + kh];
#pragma unroll
      for (int i = 0; i < 2; ++i)
#pragma unroll
        for (int j = 0; j < 2; ++j)
          acc[gg][i][j] = __builtin_amdgcn_mfma_f32_16x16x32_bf16(
              (gg < 3) ? ax[i] : ah[i], bw[j], acc[gg][i][j], 0, 0, 0);
    }
    __syncthreads();
    cur ^= 1;
  }

  const int r15 = lane & 15, rq = (lane >> 4) * 4;
#pragma unroll
  for (int j = 0; j < 2; ++j) {
    const int col = bn0 + wn * 32 + j * 16 + r15;
    const float br  = S.bih[col],        bhr = S.bhh[col];
    const float bz  = S.bih[col + 1024], bhz = S.bhh[col + 1024];
    const float bn_ = S.bih[col + 2048], bhn = S.bhh[col + 2048];
#pragma unroll
    for (int i = 0; i < 2; ++i) {
#pragma unroll
      for (int q = 0; q < 4; ++q) {
        const int row = bm0 + wm * 32 + i * 16 + rq + q;
        const float ir = acc[0][i][j][q] + br,   hr = acc[3][i][j][q] + bhr;
        const float iz = acc[1][i][j][q] + bz,   hz = acc[4][i][j][q] + bhz;
        const float in_ = acc[2][i][j][q] + bn_, hn = acc[5][i][j][q] + bhn;
        const float r = sigm(ir + hr);
        const float z = sigm(iz + hz);
        const float ng = tanhf(in_ + r * hn);
        const long long o = (long long)row * 1024 + col;
        const float bnew = (1.f - z) * ng + z * S.hf[o];
        S.dst[o] = bnew;
        S.dstb[o] = f2bf(bnew);
      }
    }
  }
}

// ---- fused 2-sided head, double-buffered ----
struct HeadSide {
  const ushort_t* hh;    // bf16 [1024x1024]
  const ushort_t* Ws;    // bf16 [512x1024]: rows [0,256)=mean, [256,512)=raw
  const float* bs;       // f32 [512]
  const float* noise;    // f32 [1024x256]
  float* omean; float* ostd; float* ostate;
  ushort_t* stateb;      // bf16 shadow [1024x256]
};
struct Head2Args { HeadSide s[2]; };

__global__ __launch_bounds__(256) void head2_k(Head2Args g) {
  const HeadSide S = g.s[blockIdx.z];
  __shared__ __align__(16) ushort_t As[2][2048];
  __shared__ __align__(16) ushort_t Wt[2][2][2048];
  const int tid = threadIdx.x;
  const int lane = tid & 63, wave = tid >> 6;
  const int wm = wave >> 1, wn = wave & 1;
  const int bn0 = blockIdx.x * 64, bm0 = blockIdx.y * 64;

  f32x4 acc[2][2][2];
#pragma unroll
  for (int gg = 0; gg < 2; ++gg)
#pragma unroll
    for (int i = 0; i < 2; ++i)
#pragma unroll
      for (int j = 0; j < 2; ++j) acc[gg][i][j] = (f32x4){0.f, 0.f, 0.f, 0.f};

  const int rowA = tid >> 2, kc = (tid & 3) * 8;
  const long long aoff = (long long)(bm0 + rowA) * 1024 + kc;

  auto stage = [&](int buf, int kt) {
    const int k0 = kt * 32;
    gld16(S.hh + aoff + k0, &As[buf][wave * 512]);
#pragma unroll
    for (int gg = 0; gg < 2; ++gg)
      gld16(S.Ws + (long long)(gg * 256 + bn0 + rowA) * 1024 + k0 + kc,
            &Wt[buf][gg][wave * 512]);
  };

  stage(0, 0);
  __syncthreads();
  int cur = 0;
#pragma unroll 1
  for (int kt = 0; kt < 32; ++kt) {
    if (kt + 1 < 32) stage(cur ^ 1, kt + 1);
    const int r15 = lane & 15, kh = (lane >> 4) * 8;
    bf16x8 a[2];
#pragma unroll
    for (int i = 0; i < 2; ++i)
      a[i] = *(const bf16x8*)&As[cur][(wm * 32 + i * 16 + r15) * 32 + kh];
#pragma unroll
    for (int gg = 0; gg < 2; ++gg) {
      bf16x8 bw[2];
#pragma unroll
      for (int j = 0; j < 2; ++j)
        bw[j] = *(const bf16x8*)&Wt[cur][gg][(wn * 32 + j * 16 + r15) * 32 + kh];
#pragma unroll
      for (int i = 0; i < 2; ++i)
#pragma unroll
        for (int j = 0; j < 2; ++j)
          acc[gg][i][j] = __builtin_amdgcn_mfma_f32_16x16x32_bf16(a[i], bw[j], acc[gg][i][j], 0, 0, 0);
    }
    __syncthreads();
    cur ^= 1;
  }

  const int r15 = lane & 15, rq = (lane >> 4) * 4;
#pragma unroll
  for (int j = 0; j < 2; ++j) {
    const int col = bn0 + wn * 32 + j * 16 + r15;   // 0..255
    const float bm = S.bs[col];
    const float bsd = S.bs[col + 256];
#pragma unroll
    for (int i = 0; i < 2; ++i) {
#pragma unroll
      for (int q = 0; q < 4; ++q) {
        const int row = bm0 + wm * 32 + i * 16 + rq + q;
        const float mean = acc[0][i][j][q] + bm;
        const float rs = acc[1][i][j][q] + bsd;
        const float sp = fmaxf(rs, 0.f) + log1pf(expf(-fabsf(rs)));
        const float sd = sp + 0.1f;
        const long long o = (long long)row * 256 + col;
        const float st = mean + sd * S.noise[o];
        S.omean[o] = mean; S.ostd[o] = sd; S.ostate[o] = st;
        S.stateb[o] = f2bf(st);
      }
    }
  }
}

extern "C" void kernel_launch(void* const* d_in, const int* in_sizes, int n_in,
                              void* d_out, int out_size, void* d_ws, size_t ws_size,
                              hipStream_t stream) {
  float* out = (float*)d_out;

  int gid = 0;
  if (n_in != 26) gid = 1;
  else if (out_size != 83886080) gid = 2;
  else if (in_sizes[0] != 262144 || in_sizes[1] != 1048576 || in_sizes[2] != 33554432 ||
           in_sizes[3] != 196608 || in_sizes[4] != 8388608 || in_sizes[5] != 8388608) gid = 3;
  else if (in_sizes[6] != 1572864 || in_sizes[8] != 548864) gid = 4;
  else if (in_sizes[10] != 3145728 || in_sizes[11] != 3145728 ||
           in_sizes[14] != 3145728 || in_sizes[15] != 3145728) gid = 5;
  else if (in_sizes[18] != 1048576 || in_sizes[20] != 524288 ||
           in_sizes[22] != 1048576 || in_sizes[24] != 524288) gid = 6;
  else if (ws_size < (128ull << 20)) gid = 7;
  if (gid != 0) {
    unsigned wsMB = (unsigned)(ws_size >> 20); if (wsMB > 4095u) wsMB = 4095u;
    const float K = (float)gid * 16777216.0f + (float)wsMB;
    hipLaunchKernelGGL(marker_k, dim3(1), dim3(64), 0, stream, out, K);
    return;
  }

  const float* prev_state  = (const float*)d_in[0];
  const float* prev_belief = (const float*)d_in[1];
  const float* observations= (const float*)d_in[2];
  const float* poses       = (const float*)d_in[3];
  const float* noise_post  = (const float*)d_in[4];
  const float* noise_prior = (const float*)d_in[5];
  const float* W_esq = (const float*)d_in[6];  const float* b_esq = (const float*)d_in[7];
  const float* W_esp = (const float*)d_in[8];  const float* b_esp = (const float*)d_in[9];
  const float* gq_wih = (const float*)d_in[10]; const float* gq_whh = (const float*)d_in[11];
  const float* gq_bih = (const float*)d_in[12]; const float* gq_bhh = (const float*)d_in[13];
  const float* gp_wih = (const float*)d_in[14]; const float* gp_whh = (const float*)d_in[15];
  const float* gp_bih = (const float*)d_in[16]; const float* gp_bhh = (const float*)d_in[17];
  const float* W_ebq = (const float*)d_in[18]; const float* b_ebq = (const float*)d_in[19];
  const float* W_sq  = (const float*)d_in[20]; const float* b_sq  = (const float*)d_in[21];
  const float* W_ebp = (const float*)d_in[22]; const float* b_ebp = (const float*)d_in[23];
  const float* W_sp  = (const float*)d_in[24]; const float* b_sp  = (const float*)d_in[25];

  float* out_belief = out;
  float* out_pstate = out + 33554432LL;
  float* out_pmean  = out + 41943040LL;
  float* out_pstd   = out + 50331648LL;
  float* out_qstate = out + 58720256LL;
  float* out_qmean  = out + 67108864LL;
  float* out_qstd   = out + 75497472LL;

  char* w = (char*)d_ws;
  ushort_t* obsb  = (ushort_t*)(w);                     // [0,64)MB
  ushort_t* wWesq = (ushort_t*)(w + (64ull << 20));     // 1024x1536
  ushort_t* wWesp = (ushort_t*)(w + (67ull << 20));     // 1024x512
  ushort_t* wGqih = (ushort_t*)(w + (68ull << 20));     // 3072x1024
  ushort_t* wGqhh = (ushort_t*)(w + (74ull << 20));
  ushort_t* wGpih = (ushort_t*)(w + (80ull << 20));
  ushort_t* wGphh = (ushort_t*)(w + (86ull << 20));
  ushort_t* wEbq  = (ushort_t*)(w + (92ull << 20));     // 1024x1024
  ushort_t* wEbp  = (ushort_t*)(w + (94ull << 20));
  ushort_t* wSq   = (ushort_t*)(w + (96ull << 20));     // 512x1024
  ushort_t* wSp   = (ushort_t*)(w + (97ull << 20));
  float*    wpe   = (float*)(w + (98ull << 20));        // 1024x6
  ushort_t* h_q   = (ushort_t*)(w + (99ull << 20));     // 1024x1024
  ushort_t* h_p   = (ushort_t*)(w + (101ull << 20));
  ushort_t* bqb[2] = { (ushort_t*)(w + (103ull << 20)), (ushort_t*)(w + (105ull << 20)) };
  ushort_t* bpb[2] = { (ushort_t*)(w + (107ull << 20)), (ushort_t*)(w + (109ull << 20)) };
  ushort_t* sqb   = (ushort_t*)(w + (111ull << 20));    // 1024x256
  ushort_t* spb   = (ushort_t*)(w + (111ull << 20) + 524288);
  float*    bpf[2] = { (float*)(w + (112ull << 20)), (float*)(w + (116ull << 20)) };

  const dim3 blk(256);
  auto cvt = [&](const float* s, ushort_t* d, long long n, int c, int ld, int off) {
    hipLaunchKernelGGL(cvt_k, dim3((unsigned)((n + 255) / 256)), blk, 0, stream, s, d, n, c, ld, off);
  };
  cvt(observations, obsb, 33554432LL, 1024, 1024, 0);
  cvt(W_esq, wWesq, 1572864LL, 1536, 1536, 0);
  cvt(W_esp, wWesp, 524288LL, 512, 536, 24);
  cvt(gq_wih, wGqih, 3145728LL, 1024, 1024, 0);
  cvt(gq_whh, wGqhh, 3145728LL, 1024, 1024, 0);
  cvt(gp_wih, wGpih, 3145728LL, 1024, 1024, 0);
  cvt(gp_whh, wGphh, 3145728LL, 1024, 1024, 0);
  cvt(W_ebq, wEbq, 1048576LL, 1024, 1024, 0);
  cvt(W_ebp, wEbp, 1048576LL, 1024, 1024, 0);
  cvt(W_sq, wSq, 524288LL, 1024, 1024, 0);
  cvt(W_sp, wSp, 524288LL, 1024, 1024, 0);
  cvt(prev_state, sqb, 262144LL, 256, 256, 0);
  cvt(prev_state, spb, 262144LL, 256, 256, 0);
  cvt(prev_belief, bqb[1], 1048576LL, 1024, 1024, 0);
  cvt(prev_belief, bpb[1], 1048576LL, 1024, 1024, 0);
  hipLaunchKernelGGL(wpe_k, dim3(24), blk, 0, stream, W_esp, wpe);

  for (int t = 0; t < T1_; ++t) {
    const int cur = t & 1, prv = cur ^ 1;
    const ushort_t* obs_t = obsb + (long long)t * 1048576;
    const float* bq_prev_f = (t == 0) ? prev_belief : out_belief + (long long)(t - 1) * 1048576;
    const float* bp_prev_f = (t == 0) ? prev_belief : bpf[prv];

    // 1) embed: z=0 h_q, z=1 h_p (+pose)
    MM2Args a{};
    a.s[0] = MMSide{ obs_t, sqb, spb, 1024, 256, 256, 0, 1024, 1280,
                     wWesq, 1536, b_esq, h_q, 0 };
    a.s[1] = MMSide{ sqb, spb, nullptr, 256, 256, 0, 0, 256, 0,
                     wWesp, 512, b_esp, h_p, 1 };
    a.poses_t = poses + (long long)t * 6144; a.wpe = wpe;
    hipLaunchKernelGGL(mm2_k, dim3(8, 16, 2), blk, 0, stream, a);

    // 2) GRU: z=0 posterior (-> out ch0[t], bqb[cur]); z=1 prior (-> bpf[cur], bpb[cur])
    Gru2Args gr{};
    gr.s[0] = GruSide{ h_q, bqb[prv], bq_prev_f, wGqih, wGqhh, gq_bih, gq_bhh,
                       out_belief + (long long)t * 1048576, bqb[cur] };
    gr.s[1] = GruSide{ h_p, bpb[prv], bp_prev_f, wGpih, wGphh, gp_bih, gp_bhh,
                       bpf[cur], bpb[cur] };
    hipLaunchKernelGGL(gru2_k, dim3(16, 8, 2), dim3(512), 0, stream, gr);

    // 3) belief->hidden: z=0 hh_q -> h_q, z=1 hh_p -> h_p
    a = MM2Args{};
    a.s[0] = MMSide{ bqb[cur], nullptr, nullptr, 1024, 0, 0, 0, 0, 0,
                     wEbq, 1024, b_ebq, h_q, 0 };
    a.s[1] = MMSide{ bpb[cur], nullptr, nullptr, 1024, 0, 0, 0, 0, 0,
                     wEbp, 1024, b_ebp, h_p, 0 };
    hipLaunchKernelGGL(mm2_k, dim3(8, 16, 2), blk, 0, stream, a);

    // 4) heads: z=0 posterior (qmean/qstd/qstate + sqb), z=1 prior
    Head2Args hd{};
    hd.s[0] = HeadSide{ h_q, wSq, b_sq, noise_post + (long long)t * 262144,
                        out_qmean + (long long)t * 262144,
                        out_qstd + (long long)t * 262144,
                        out_qstate + (long long)t * 262144, sqb };
    hd.s[1] = HeadSide{ h_p, wSp, b_sp, noise_prior + (long long)t * 262144,
                        out_pmean + (long long)t * 262144,
                        out_pstd + (long long)t * 262144,
                        out_pstate + (long long)t * 262144, spb };
    hipLaunchKernelGGL(head2_k, dim3(4, 16, 2), blk, 0, stream, hd);
  }
}